// Round 1
// baseline (107.165 us; speedup 1.0000x reference)
//
#include <hip/hip_runtime.h>
#include <hip/hip_bf16.h>

#define LL 2048
#define CC 64

typedef __bf16 bf16x8 __attribute__((ext_vector_type(8)));
typedef float f32x4 __attribute__((ext_vector_type(4)));
typedef unsigned short ushort8 __attribute__((ext_vector_type(8)));

union BU { ushort8 u; bf16x8 b; };

__device__ __forceinline__ unsigned short f2bf(float f) {
  unsigned int x = __float_as_uint(f);
  return (unsigned short)((x + 0x7fffu + ((x >> 16) & 1u)) >> 16);
}

__global__ void zero_ws_k(float* ws) { ws[threadIdx.x] = 0.f; }

__global__ __launch_bounds__(256) void l2disc_main(
    const float* __restrict__ times, const float* __restrict__ path1,
    const float* __restrict__ path2, const float* __restrict__ Amat,
    float* __restrict__ wsacc)
{
  const int lane = threadIdx.x & 63;
  const int wave = threadIdx.x >> 6;
  const int c = lane & 15;       // output-channel sub-index / row-within-tile for loads
  const int g = lane >> 4;       // k-group
  const int b = blockIdx.x >> 2;
  const int q = ((blockIdx.x & 3) << 2) | wave;  // 0..15: which 128-row span
  const int p0 = q << 7;                          // first pair index owned
  const int p1 = min(p0 + 128, LL - 1);           // pairs [p0, p1)

  // ---- B-fragments: Bfrag[k, n] = A[n=16t+c][j = 32s + g*8 + e] (same k-bijection as A-frag)
  bf16x8 bf[4][2];
  #pragma unroll
  for (int t = 0; t < 4; ++t) {
    #pragma unroll
    for (int s = 0; s < 2; ++s) {
      const float* ap = Amat + (16 * t + c) * CC + 32 * s + g * 8;
      float4 x0 = *(const float4*)ap;
      float4 x1 = *(const float4*)(ap + 4);
      BU u;
      u.u[0] = f2bf(x0.x); u.u[1] = f2bf(x0.y); u.u[2] = f2bf(x0.z); u.u[3] = f2bf(x0.w);
      u.u[4] = f2bf(x1.x); u.u[5] = f2bf(x1.y); u.u[6] = f2bf(x1.z); u.u[7] = f2bf(x1.w);
      bf[t][s] = u.b;
    }
  }

  float wacc = 0.f;
  f32x4 prev = {0.f, 0.f, 0.f, 0.f};  // prev[t] = y[row r0-1][chan c+16t], broadcast to all lanes

  const int ntile = (q == 15) ? 8 : 9;  // tile 8 = 1-row overlap for the boundary pair
  for (int i = 0; i < ntile; ++i) {
    const int r0 = p0 + (i << 4);
    const int row = r0 + c;

    bf16x8 af0, af1;
    if (i < 8 || c == 0) {
      const float* pp1 = path1 + ((size_t)b * LL + row) * CC + g * 8;
      const float* pp2 = path2 + (size_t)row * CC + g * 8;
      float4 a0 = *(const float4*)(pp1);
      float4 a1 = *(const float4*)(pp1 + 4);
      float4 a2 = *(const float4*)(pp1 + 32);
      float4 a3 = *(const float4*)(pp1 + 36);
      float4 b0 = *(const float4*)(pp2);
      float4 b1 = *(const float4*)(pp2 + 4);
      float4 b2 = *(const float4*)(pp2 + 32);
      float4 b3 = *(const float4*)(pp2 + 36);
      BU u0, u1;
      u0.u[0] = f2bf(a0.x - b0.x); u0.u[1] = f2bf(a0.y - b0.y);
      u0.u[2] = f2bf(a0.z - b0.z); u0.u[3] = f2bf(a0.w - b0.w);
      u0.u[4] = f2bf(a1.x - b1.x); u0.u[5] = f2bf(a1.y - b1.y);
      u0.u[6] = f2bf(a1.z - b1.z); u0.u[7] = f2bf(a1.w - b1.w);
      u1.u[0] = f2bf(a2.x - b2.x); u1.u[1] = f2bf(a2.y - b2.y);
      u1.u[2] = f2bf(a2.z - b2.z); u1.u[3] = f2bf(a2.w - b2.w);
      u1.u[4] = f2bf(a3.x - b3.x); u1.u[5] = f2bf(a3.y - b3.y);
      u1.u[6] = f2bf(a3.z - b3.z); u1.u[7] = f2bf(a3.w - b3.w);
      af0 = u0.b; af1 = u1.b;
    } else {
      BU z; ushort8 z8 = {0,0,0,0,0,0,0,0}; z.u = z8;
      af0 = z.b; af1 = z.b;
    }

    f32x4 y[4];
    #pragma unroll
    for (int t = 0; t < 4; ++t) { f32x4 zz = {0.f,0.f,0.f,0.f}; y[t] = zz; }
    #pragma unroll
    for (int t = 0; t < 4; ++t)
      y[t] = __builtin_amdgcn_mfma_f32_16x16x32_bf16(af0, bf[t][0], y[t], 0, 0, 0);
    #pragma unroll
    for (int t = 0; t < 4; ++t)
      y[t] = __builtin_amdgcn_mfma_f32_16x16x32_bf16(af1, bf[t][1], y[t], 0, 0, 0);

    // ---- in-lane adjacent-row pairs: rows (4g+r, 4g+r+1), r=0..2
    #pragma unroll
    for (int r = 0; r < 3; ++r) {
      const int l = r0 + (g << 2) + r;
      if (l < p1) {
        const float dt = times[l + 1] - times[l];
        float s = 0.f;
        #pragma unroll
        for (int t = 0; t < 4; ++t) {
          float a = y[t][r], bb = y[t][r + 1];
          s += a * a + a * bb + bb * bb;
        }
        wacc += dt * s;
      }
    }

    // ---- cross-reg-group pair: rows (4g+3, 4g+4) via lane+16 (unconditional shfl)
    {
      float nb0 = __shfl_down(y[0][0], 16);
      float nb1 = __shfl_down(y[1][0], 16);
      float nb2 = __shfl_down(y[2][0], 16);
      float nb3 = __shfl_down(y[3][0], 16);
      const int l = r0 + (g << 2) + 3;
      if (g < 3 && l < p1) {
        const float dt = times[l + 1] - times[l];
        float a, s = 0.f;
        a = y[0][3]; s += a * a + a * nb0 + nb0 * nb0;
        a = y[1][3]; s += a * a + a * nb1 + nb1 * nb1;
        a = y[2][3]; s += a * a + a * nb2 + nb2 * nb2;
        a = y[3][3]; s += a * a + a * nb3 + nb3 * nb3;
        wacc += dt * s;
      }
    }

    // ---- cross-tile pair: rows (r0-1, r0), using saved prev (only g==0 lanes count it)
    if (i > 0) {
      const int l = r0 - 1;
      if (g == 0 && l < p1) {
        const float dt = times[l + 1] - times[l];
        float s = 0.f;
        #pragma unroll
        for (int t = 0; t < 4; ++t) {
          float a = prev[t], bb = y[t][0];
          s += a * a + a * bb + bb * bb;
        }
        wacc += dt * s;
      }
    }

    // ---- save row r0+15 (held by g==3 lanes, reg 3) broadcast to every lane's channel slot
    #pragma unroll
    for (int t = 0; t < 4; ++t) prev[t] = __shfl(y[t][3], 48 + c);
  }

  // ---- wave reduce + one atomic per wave
  #pragma unroll
  for (int off = 32; off > 0; off >>= 1) wacc += __shfl_down(wacc, off);
  if (lane == 0) atomicAdd(wsacc + b, wacc);
}

__global__ void fin_k(const float* __restrict__ ws, float* __restrict__ out, int n) {
  int i = blockIdx.x * blockDim.x + threadIdx.x;
  if (i < n) out[i] = sqrtf(ws[i] * (1.0f / 3.0f));
}

extern "C" void kernel_launch(void* const* d_in, const int* in_sizes, int n_in,
                              void* d_out, int out_size, void* d_ws, size_t ws_size,
                              hipStream_t stream) {
  const float* times = (const float*)d_in[0];
  const float* path1 = (const float*)d_in[1];
  const float* path2 = (const float*)d_in[2];
  const float* Amat  = (const float*)d_in[3];
  float* out = (float*)d_out;
  float* ws  = (float*)d_ws;
  const int B = in_sizes[1] / (LL * CC);  // 512

  hipLaunchKernelGGL(zero_ws_k, dim3(1), dim3(B), 0, stream, ws);
  hipLaunchKernelGGL(l2disc_main, dim3(B * 4), dim3(256), 0, stream,
                     times, path1, path2, Amat, ws);
  hipLaunchKernelGGL(fin_k, dim3((B + 255) / 256), dim3(256), 0, stream, ws, out, B);
}

// Round 2
// 98.043 us; speedup vs baseline: 1.0930x; 1.0930x over previous
//
#include <hip/hip_runtime.h>
#include <hip/hip_bf16.h>

#define LL 2048
#define CC 64

typedef __bf16 bf16x8 __attribute__((ext_vector_type(8)));
typedef float f32x4 __attribute__((ext_vector_type(4)));

__global__ void zero_ws_k(float* ws, int n) {
  int i = blockIdx.x * blockDim.x + threadIdx.x;
  if (i < n) ws[i] = 0.f;
}

// native RNE casts -> compiler emits v_cvt_pk_bf16_f32 (gfx950)
__device__ __forceinline__ bf16x8 mk8(f32x4 lo, f32x4 hi) {
  bf16x8 r;
  r[0] = (__bf16)lo[0]; r[1] = (__bf16)lo[1]; r[2] = (__bf16)lo[2]; r[3] = (__bf16)lo[3];
  r[4] = (__bf16)hi[0]; r[5] = (__bf16)hi[1]; r[6] = (__bf16)hi[2]; r[7] = (__bf16)hi[3];
  return r;
}

__global__ __launch_bounds__(256, 4) void l2disc_main(
    const float* __restrict__ times, const float* __restrict__ path1,
    const float* __restrict__ path2, const float* __restrict__ Amat,
    float* __restrict__ wsacc)
{
  const int lane = threadIdx.x & 63;
  const int wave = threadIdx.x >> 6;
  const int c = lane & 15;      // A-frag row within tile / output channel sub-index
  const int g = lane >> 4;      // k-group / row-quad index in C/D
  const int bp = blockIdx.x >> 2;           // batch pair 0..255
  const int b0 = bp << 1;                   // batches b0, b0+1
  const int q  = ((blockIdx.x & 3) << 2) | wave;  // span 0..15
  const int p0 = q << 7;                    // first pair index owned

  // ---- B-operand fragments from A (same k-bijection on A- and B-frags)
  bf16x8 bfr[4][2];
  #pragma unroll
  for (int t = 0; t < 4; ++t) {
    #pragma unroll
    for (int s = 0; s < 2; ++s) {
      const float* ap = Amat + (16 * t + c) * CC + 32 * s + (g << 3);
      f32x4 x0 = *(const f32x4*)ap;
      f32x4 x1 = *(const f32x4*)(ap + 4);
      bfr[t][s] = mk8(x0, x1);
    }
  }

  float wacc0 = 0.f, wacc1 = 0.f;
  f32x4 prev0 = {0.f,0.f,0.f,0.f}, prev1 = {0.f,0.f,0.f,0.f};

  const float* p1base0 = path1 + (size_t)b0 * LL * CC;
  const float* p1base1 = p1base0 + (size_t)LL * CC;

  const int ntile = (q == 15) ? 8 : 9;   // tile 8 = 1-row overlap for boundary pair
  for (int i = 0; i < ntile; ++i) {
    const int r0 = p0 + (i << 4);
    const int row = r0 + c;
    const bool full = (i < 8);

    // ---- dt values from registers (aligned float4 + 2 scalars, all L1/L2-hot)
    f32x4 t4 = *(const f32x4*)(times + r0 + (g << 2));
    float t5  = times[min(r0 + (g << 2) + 4, LL - 1)];
    float tm1 = times[max(r0 - 1, 0)];
    const float d0 = t4[1] - t4[0], d1 = t4[2] - t4[1], d2 = t4[3] - t4[2];
    const float d3 = t5 - t4[3];
    const float dm1 = t4[0] - tm1;   // valid on g==0 lanes only (t4[0]=times[r0])

    // ---- loads: path2 once, path1 for both batches
    f32x4 p2v[4], p1a[4], p1b[4];
    if (full || c == 0) {
      const float* pp2 = path2 + (size_t)row * CC + (g << 3);
      p2v[0] = *(const f32x4*)(pp2);      p2v[1] = *(const f32x4*)(pp2 + 4);
      p2v[2] = *(const f32x4*)(pp2 + 32); p2v[3] = *(const f32x4*)(pp2 + 36);
      const float* pa = p1base0 + (size_t)row * CC + (g << 3);
      p1a[0] = *(const f32x4*)(pa);       p1a[1] = *(const f32x4*)(pa + 4);
      p1a[2] = *(const f32x4*)(pa + 32);  p1a[3] = *(const f32x4*)(pa + 36);
      const float* pb = p1base1 + (size_t)row * CC + (g << 3);
      p1b[0] = *(const f32x4*)(pb);       p1b[1] = *(const f32x4*)(pb + 4);
      p1b[2] = *(const f32x4*)(pb + 32);  p1b[3] = *(const f32x4*)(pb + 36);
    } else {
      f32x4 z = {0.f,0.f,0.f,0.f};
      #pragma unroll
      for (int t = 0; t < 4; ++t) { p2v[t] = z; p1a[t] = z; p1b[t] = z; }
    }

    // ---- per-batch: convert -> 8 MFMA -> pair sums
    auto do_batch = [&](const f32x4* p1v, f32x4& prev, float& wacc) {
      bf16x8 af0 = mk8(p1v[0] - p2v[0], p1v[1] - p2v[1]);
      bf16x8 af1 = mk8(p1v[2] - p2v[2], p1v[3] - p2v[3]);

      f32x4 y[4];
      #pragma unroll
      for (int t = 0; t < 4; ++t) { f32x4 zz = {0.f,0.f,0.f,0.f}; y[t] = zz; }
      #pragma unroll
      for (int t = 0; t < 4; ++t)
        y[t] = __builtin_amdgcn_mfma_f32_16x16x32_bf16(af0, bfr[t][0], y[t], 0, 0, 0);
      #pragma unroll
      for (int t = 0; t < 4; ++t)
        y[t] = __builtin_amdgcn_mfma_f32_16x16x32_bf16(af1, bfr[t][1], y[t], 0, 0, 0);

      if (full) {
        // in-lane adjacent pairs: rows (4g+r, 4g+r+1), r=0..2
        float s0 = 0.f, s1 = 0.f, s2 = 0.f;
        #pragma unroll
        for (int t = 0; t < 4; ++t) {
          float a, b;
          a = y[t][0]; b = y[t][1]; s0 += a*a + a*b + b*b;
          a = y[t][1]; b = y[t][2]; s1 += a*a + a*b + b*b;
          a = y[t][2]; b = y[t][3]; s2 += a*a + a*b + b*b;
        }
        wacc += d0 * s0 + d1 * s1 + d2 * s2;
        // cross-reg-group pair: rows (4g+3, 4g+4) via lane+16
        float nb0 = __shfl_down(y[0][0], 16);
        float nb1 = __shfl_down(y[1][0], 16);
        float nb2 = __shfl_down(y[2][0], 16);
        float nb3 = __shfl_down(y[3][0], 16);
        if (g < 3) {
          float a, s = 0.f;
          a = y[0][3]; s += a*a + a*nb0 + nb0*nb0;
          a = y[1][3]; s += a*a + a*nb1 + nb1*nb1;
          a = y[2][3]; s += a*a + a*nb2 + nb2*nb2;
          a = y[3][3]; s += a*a + a*nb3 + nb3*nb3;
          wacc += d3 * s;
        }
      }
      // cross-tile pair: rows (r0-1, r0) — only g==0 lanes hold row r0 in y[t][0]
      if (i > 0 && g == 0) {
        float s = 0.f;
        #pragma unroll
        for (int t = 0; t < 4; ++t) {
          float a = prev[t], b = y[t][0];
          s += a*a + a*b + b*b;
        }
        wacc += dm1 * s;
      }
      if (full) {
        // save row r0+15 (g==3 lanes, reg 3), broadcast to each lane's channel slot
        #pragma unroll
        for (int t = 0; t < 4; ++t) prev[t] = __shfl(y[t][3], 48 + c);
      }
    };

    do_batch(p1a, prev0, wacc0);
    do_batch(p1b, prev1, wacc1);
  }

  // ---- wave reduce + one atomic per wave per batch
  #pragma unroll
  for (int off = 32; off > 0; off >>= 1) {
    wacc0 += __shfl_down(wacc0, off);
    wacc1 += __shfl_down(wacc1, off);
  }
  if (lane == 0) {
    atomicAdd(wsacc + b0,     wacc0);
    atomicAdd(wsacc + b0 + 1, wacc1);
  }
}

__global__ void fin_k(const float* __restrict__ ws, float* __restrict__ out, int n) {
  int i = blockIdx.x * blockDim.x + threadIdx.x;
  if (i < n) out[i] = sqrtf(ws[i] * (1.0f / 3.0f));
}

extern "C" void kernel_launch(void* const* d_in, const int* in_sizes, int n_in,
                              void* d_out, int out_size, void* d_ws, size_t ws_size,
                              hipStream_t stream) {
  const float* times = (const float*)d_in[0];
  const float* path1 = (const float*)d_in[1];
  const float* path2 = (const float*)d_in[2];
  const float* Amat  = (const float*)d_in[3];
  float* out = (float*)d_out;
  float* ws  = (float*)d_ws;
  const int B = in_sizes[1] / (LL * CC);  // 512

  hipLaunchKernelGGL(zero_ws_k, dim3((B + 255) / 256), dim3(256), 0, stream, ws, B);
  hipLaunchKernelGGL(l2disc_main, dim3((B / 2) * 4), dim3(256), 0, stream,
                     times, path1, path2, Amat, ws);
  hipLaunchKernelGGL(fin_k, dim3((B + 255) / 256), dim3(256), 0, stream, ws, out, B);
}